// Round 2
// 156.838 us; speedup vs baseline: 1.1580x; 1.1580x over previous
//
#include <hip/hip_runtime.h>
#include <hip/hip_bf16.h>

#define B_SZ 8
#define T_SZ 1024
#define D_IN 512
#define D_H  64
#define N_H  8

typedef __hip_bfloat16 bf16;
using short8  = __attribute__((ext_vector_type(8))) short;
using short4v = __attribute__((ext_vector_type(4))) short;
using f32x4   = __attribute__((ext_vector_type(4))) float;

__device__ __forceinline__ unsigned short f2bf(float f) {
    union { __hip_bfloat16 b; unsigned short u; } c;
    c.b = __float2bfloat16(f);
    return c.u;
}

// ---------------------------------------------------------------------------
// Weight transpose: W[i(k)][d][h] fp32 -> Wt[mat][h][d][k] bf16 (1.5 MB).
// grid (512*512/256, 3). Coalesced reads; scattered bf16 writes (L2 absorbs).
// ---------------------------------------------------------------------------
__global__ __launch_bounds__(256) void wt_kernel(
    const float* __restrict__ Wk, const float* __restrict__ Wq,
    const float* __restrict__ Wv, unsigned short* __restrict__ Wt)
{
    const int mat = blockIdx.y;
    const float* W = (mat == 0) ? Wk : (mat == 1) ? Wq : Wv;
    int idx = blockIdx.x * 256 + threadIdx.x;      // over 512*512
    float v = W[idx];
    int k = idx >> 9, c = idx & 511;               // c = d*8 + h
    int h = c & 7, d = c >> 3;
    Wt[(((size_t)mat * 8 + h) * 64 + d) * 512 + k] = f2bf(v);
}

// ---------------------------------------------------------------------------
// MFMA projection: P[b][h][t][d] = sum_k X[b][t][k] * W[k][d][h], bf16 out.
// grid (8192/128, 3*8). Block: 128 rows x 64 cols, K=512 in chunks of 64.
// LDS rows padded to 72 bf16 (b128 frag reads bank-balanced). UNCHANGED this
// round (isolating the attn delta).
// ---------------------------------------------------------------------------
__global__ __launch_bounds__(256) void proj_kernel(
    const float* __restrict__ keys, const float* __restrict__ queries,
    const float* __restrict__ values,
    const unsigned short* __restrict__ Wt, unsigned short* __restrict__ KQVb)
{
    const int tid = threadIdx.x;
    const int m0  = blockIdx.x * 128;
    const int mh  = blockIdx.y;
    const int mat = mh >> 3, h = mh & 7;

    const float* X = (mat == 0) ? keys : (mat == 1) ? queries : values;
    const unsigned short* WT = Wt + (size_t)mh * (64 * 512);   // [d][k]
    unsigned short* P = KQVb + (size_t)mat * ((size_t)B_SZ * N_H * T_SZ * D_H);

    __shared__ __align__(16) unsigned short Xst[128 * 72];
    __shared__ __align__(16) unsigned short Wst[64 * 72];

    const int wid = tid >> 6, lane = tid & 63;
    const int quad = lane >> 4, l15 = lane & 15;

    f32x4 acc[2][4];
    #pragma unroll
    for (int a = 0; a < 2; ++a)
        #pragma unroll
        for (int n = 0; n < 4; ++n) acc[a][n] = (f32x4){0.f, 0.f, 0.f, 0.f};

    const float4* X4 = (const float4*)X;

    for (int kc = 0; kc < 8; ++kc) {
        const int k0 = kc * 64;
        __syncthreads();
        // stage X: 128 rows x 64 k, fp32 -> bf16
        #pragma unroll
        for (int q2 = 0; q2 < 8; ++q2) {
            int e = tid + q2 * 256;                 // 0..2047 float4s
            int r = e >> 4, c4 = e & 15;
            float4 v = X4[(size_t)(m0 + r) * (D_IN / 4) + (k0 >> 2) + c4];
            short4v s = {(short)f2bf(v.x), (short)f2bf(v.y),
                         (short)f2bf(v.z), (short)f2bf(v.w)};
            *(short4v*)&Xst[r * 72 + c4 * 4] = s;
        }
        // stage Wt tile: 64 d x 64 k, b128 copies
        #pragma unroll
        for (int q2 = 0; q2 < 2; ++q2) {
            int e = tid + q2 * 256;                 // 0..511 short8 units
            int d = e >> 3, ch = e & 7;
            *(short8*)&Wst[d * 72 + ch * 8] =
                *(const short8*)&WT[(size_t)d * 512 + k0 + ch * 8];
        }
        __syncthreads();
        // MFMA: wave strip = rows [wid*32, wid*32+31]
        #pragma unroll
        for (int ic = 0; ic < 2; ++ic) {
            short8 a0 = *(const short8*)&Xst[(wid*32      + l15) * 72 + ic*32 + quad*8];
            short8 a1 = *(const short8*)&Xst[(wid*32 + 16 + l15) * 72 + ic*32 + quad*8];
            #pragma unroll
            for (int nt = 0; nt < 4; ++nt) {
                short8 bf = *(const short8*)&Wst[(nt*16 + l15) * 72 + ic*32 + quad*8];
                acc[0][nt] = __builtin_amdgcn_mfma_f32_16x16x32_bf16(a0, bf, acc[0][nt], 0, 0, 0);
                acc[1][nt] = __builtin_amdgcn_mfma_f32_16x16x32_bf16(a1, bf, acc[1][nt], 0, 0, 0);
            }
        }
    }

    // epilogue: rows m = m0 + wid*32 + mt*16 + quad*4 + r; cols d = nt*16 + l15
    #pragma unroll
    for (int mt = 0; mt < 2; ++mt)
        #pragma unroll
        for (int r = 0; r < 4; ++r) {
            int mrow = m0 + wid * 32 + mt * 16 + quad * 4 + r;
            int bb = mrow >> 10, t = mrow & 1023;
            size_t base = (((size_t)(bb * N_H + h)) * T_SZ + t) * D_H;
            #pragma unroll
            for (int nt = 0; nt < 4; ++nt)
                P[base + nt * 16 + l15] = f2bf(acc[mt][nt][r]);
        }
}

// ---------------------------------------------------------------------------
// MFMA flash attention, v2b (v2 with exp2f hardening).
//   grid (512): bid = pair*64 + b*8 + h  (bid%8 == h -> per-XCD K/V L2 reuse)
//   block 512 threads = 8 waves: waves 0-3 own j-strip (15-pair)*64 (long),
//   waves 4-7 own j-strip pair*64 (short) -> every block = 17 tile-units,
//   perfectly uniform (no causal tail).
// Per 64-key tile:
//   - K/V/pad staged double-buffered; next tile's global loads issued BEFORE
//     compute, LDS-written AFTER (latency hidden); ONE barrier per tile.
//   - QK^T: A=K rows, B=Q rows (Q frags held in registers, loaded once).
//   - online softmax in exp2 domain (scale 0.125*log2e folded in); pad mask
//     read as per-quad float4 broadcast only on tiles containing padding;
//     causal compare only on diagonal tiles.
//   - PV: A = V^T staged with key-columns PERMUTED (c = i3*16+i2*8+i4*4+i1i0)
//     so the MFMA contraction order equals the QK^T output register order ->
//     B-frag = direct pack of p[0..15]. No P LDS round-trip at all.
//   - fully-padded key tiles (key_seq==-1 across the tile) are skipped
//     (their contribution is exp(~-125) == 0 in fp32).
// Output fp32 out[b][j][h*64+d], float4 stores.
// ---------------------------------------------------------------------------
#define SCALE  0.18033688f      /* (1/sqrt(64)) * log2(e) */
#define MASKV -180.33688f       /* -1000 * SCALE          */

__global__ __launch_bounds__(512, 4) void attn_kernel(
    const unsigned short* __restrict__ Qb, const unsigned short* __restrict__ Kb,
    const unsigned short* __restrict__ Vb,
    const int* __restrict__ key_seq, float* __restrict__ out)
{
    const int tid  = threadIdx.x;
    const int bid  = blockIdx.x;
    const int pair = bid >> 6;              // 0..7
    const int b    = (bid >> 3) & 7;
    const int h    = bid & 7;               // == bid%8 -> XCD id
    const int wid  = tid >> 6, lane = tid & 63;
    const int quad = lane >> 4, l15 = lane & 15;

    __shared__ __align__(16) unsigned short Kst[2][64 * 72];
    __shared__ __align__(16) unsigned short VTst[2][64 * 72];
    __shared__ __align__(16) float spadf[2][64];
    __shared__ int tflags[16];

    const size_t bh = (size_t)(b * N_H + h) * T_SZ;

    // strip assignment: waves 0-3 -> long strip, waves 4-7 -> short strip
    const int strip_j0 = (wid < 4) ? (15 - pair) * 64 : pair * 64;
    const int j0w = strip_j0 + (wid & 3) * 16;
    const int jg  = j0w + l15;
    const int ntmax = 16 - pair;            // long strip needs tiles 0..ntmax-1

    // Q fragments straight from global (one-time; no LDS staging)
    short8 qf0 = *(const short8*)&Qb[(bh + jg) * D_H + quad * 8];
    short8 qf1 = *(const short8*)&Qb[(bh + jg) * D_H + 32 + quad * 8];

    // per-tile flags: bit0 = any valid key, bit1 = any padded key
    {
        int ka  = key_seq[b * T_SZ + wid * 64 + lane];
        int kb2 = key_seq[b * T_SZ + 512 + wid * 64 + lane];
        unsigned long long ba  = __ballot(ka  != -1);
        unsigned long long bb2 = __ballot(kb2 != -1);
        if (lane == 0) {
            tflags[wid]     = (ba  != 0ull ? 1 : 0) | (ba  != ~0ull ? 2 : 0);
            tflags[8 + wid] = (bb2 != 0ull ? 1 : 0) | (bb2 != ~0ull ? 2 : 0);
        }
    }

    // staging coordinates
    const int sk_row = tid >> 3, sk_c = tid & 7;        // K: 64 rows x 8 chunks
    const int sv_i = lane, sv_ch = wid;                  // V: col i, d-chunk ch
    // permuted V^T column: c = i3*16 + i2*8 + i4*4 + i1i0 (+ i5) so that the
    // MFMA contraction order equals the p[] register order
    const int sv_col = (sv_i & 3) | ((sv_i & 16) >> 2) | ((sv_i & 4) << 1)
                     | ((sv_i & 8) << 1) | (sv_i & 32);

    // issue tile-0 loads
    short8 kreg = *(const short8*)&Kb[(bh + sk_row) * D_H + sk_c * 8];
    short8 vreg = *(const short8*)&Vb[(bh + sv_i) * D_H + sv_ch * 8];
    int ksv = (tid < 64) ? key_seq[b * T_SZ + tid] : -1;

    __syncthreads();                        // tflags ready

    unsigned tmask = 1u, pmask = 0u;
    #pragma unroll
    for (int t = 0; t < 16; ++t) {
        int f = tflags[t];
        tmask |= (unsigned)(f & 1) << t;
        pmask |= (unsigned)((f >> 1) & 1) << t;
    }
    tmask &= (unsigned)((1ull << ntmax) - 1ull);
    tmask |= 1u;                            // tile 0 always processed

    // write tile 0 into buffer 0
    *(short8*)&Kst[0][sk_row * 72 + sk_c * 8] = kreg;
    #pragma unroll
    for (int e = 0; e < 8; ++e)
        VTst[0][(sv_ch * 8 + e) * 72 + sv_col] = (unsigned short)vreg[e];
    if (tid < 64) spadf[0][tid] = (ksv == -1) ? MASKV : 0.f;
    __syncthreads();

    float m = -1e30f, l = 0.f;
    f32x4 o0 = {0.f,0.f,0.f,0.f}, o1 = o0, o2 = o0, o3 = o0;

    unsigned rem = tmask & ~1u;
    int tcur = 0, nb = 0;
    for (;;) {
        // ---- issue next tile's global loads (latency hides under compute) ----
        int tnext = -1;
        if (rem) { tnext = __ffs((int)rem) - 1; rem &= rem - 1; }
        if (tnext >= 0) {
            const size_t r0 = bh + tnext * 64;
            kreg = *(const short8*)&Kb[(r0 + sk_row) * D_H + sk_c * 8];
            vreg = *(const short8*)&Vb[(r0 + sv_i) * D_H + sv_ch * 8];
            if (tid < 64) ksv = key_seq[b * T_SZ + tnext * 64 + tid];
        }

        // ---- compute tile tcur from buffer nb ----
        const int i0 = tcur * 64;
        if (i0 <= j0w + 15) {                           // wave has unmasked rows
            const bool haspad = (pmask >> tcur) & 1u;
            const bool needC  = (i0 + 63 > j0w);        // diagonal tile only
            float sv[16];
            #pragma unroll
            for (int it = 0; it < 4; ++it) {
                f32x4 s = {0.f,0.f,0.f,0.f};
                short8 a0 = *(const short8*)&Kst[nb][(it*16 + l15) * 72 + quad*8];
                s = __builtin_amdgcn_mfma_f32_16x16x32_bf16(a0, qf0, s, 0, 0, 0);
                short8 a1 = *(const short8*)&Kst[nb][(it*16 + l15) * 72 + 32 + quad*8];
                s = __builtin_amdgcn_mfma_f32_16x16x32_bf16(a1, qf1, s, 0, 0, 0);
                f32x4 sp = {0.f,0.f,0.f,0.f};
                if (haspad) sp = *(const f32x4*)&spadf[nb][it*16 + quad*4];
                #pragma unroll
                for (int r = 0; r < 4; ++r) {
                    float v = __builtin_fmaf(s[r], SCALE, sp[r]);
                    if (needC && (i0 + it*16 + quad*4 + r > jg)) v += MASKV;
                    sv[it*4 + r] = v;
                }
            }

            // online softmax over i (per j = l15; i spans regs + quads)
            float mt = sv[0];
            #pragma unroll
            for (int k = 1; k < 16; ++k) mt = fmaxf(mt, sv[k]);
            mt = fmaxf(mt, __shfl_xor(mt, 16));
            mt = fmaxf(mt, __shfl_xor(mt, 32));
            const float mnew  = fmaxf(m, mt);
            const float alpha = exp2f(m - mnew);
            float p[16], ls = 0.f;
            #pragma unroll
            for (int k = 0; k < 16; ++k) {
                p[k] = exp2f(sv[k] - mnew);
                ls += p[k];
            }
            ls += __shfl_xor(ls, 16);
            ls += __shfl_xor(ls, 32);
            l = l * alpha + ls;
            m = mnew;
            o0 *= alpha; o1 *= alpha; o2 *= alpha; o3 *= alpha;

            // PV B-frags directly from registers (V columns pre-permuted)
            short8 pf0, pf1;
            #pragma unroll
            for (int e = 0; e < 8; ++e) {
                pf0[e] = (short)f2bf(p[e]);
                pf1[e] = (short)f2bf(p[8 + e]);
            }
            short8 a;
            a = *(const short8*)&VTst[nb][(     l15) * 72 +      quad * 8];
            o0 = __builtin_amdgcn_mfma_f32_16x16x32_bf16(a, pf0, o0, 0, 0, 0);
            a = *(const short8*)&VTst[nb][(     l15) * 72 + 32 + quad * 8];
            o0 = __builtin_amdgcn_mfma_f32_16x16x32_bf16(a, pf1, o0, 0, 0, 0);
            a = *(const short8*)&VTst[nb][(16 + l15) * 72 +      quad * 8];
            o1 = __builtin_amdgcn_mfma_f32_16x16x32_bf16(a, pf0, o1, 0, 0, 0);
            a = *(const short8*)&VTst[nb][(16 + l15) * 72 + 32 + quad * 8];
            o1 = __builtin_amdgcn_mfma_f32_16x16x32_bf16(a, pf1, o1, 0, 0, 0);
            a = *(const short8*)&VTst[nb][(32 + l15) * 72 +      quad * 8];
            o2 = __builtin_amdgcn_mfma_f32_16x16x32_bf16(a, pf0, o2, 0, 0, 0);
            a = *(const short8*)&VTst[nb][(32 + l15) * 72 + 32 + quad * 8];
            o2 = __builtin_amdgcn_mfma_f32_16x16x32_bf16(a, pf1, o2, 0, 0, 0);
            a = *(const short8*)&VTst[nb][(48 + l15) * 72 +      quad * 8];
            o3 = __builtin_amdgcn_mfma_f32_16x16x32_bf16(a, pf0, o3, 0, 0, 0);
            a = *(const short8*)&VTst[nb][(48 + l15) * 72 + 32 + quad * 8];
            o3 = __builtin_amdgcn_mfma_f32_16x16x32_bf16(a, pf1, o3, 0, 0, 0);
        }

        if (tnext < 0) break;

        // ---- write next tile into the other buffer (T14 late-write) ----
        const int nb2 = nb ^ 1;
        *(short8*)&Kst[nb2][sk_row * 72 + sk_c * 8] = kreg;
        #pragma unroll
        for (int e = 0; e < 8; ++e)
            VTst[nb2][(sv_ch * 8 + e) * 72 + sv_col] = (unsigned short)vreg[e];
        if (tid < 64) spadf[nb2][tid] = (ksv == -1) ? MASKV : 0.f;
        __syncthreads();                     // single barrier per tile
        tcur = tnext; nb = nb2;
    }

    // epilogue: lane j = jg, d = dblk*16 + quad*4 + r -> float4 stores
    const float inv = 1.f / l;
    float* op = out + ((size_t)b * T_SZ + jg) * (N_H * D_H) + h * D_H + quad * 4;
    *(f32x4*)(op +  0) = o0 * inv;
    *(f32x4*)(op + 16) = o1 * inv;
    *(f32x4*)(op + 32) = o2 * inv;
    *(f32x4*)(op + 48) = o3 * inv;
}

// ---------------------------------------------------------------------------
extern "C" void kernel_launch(void* const* d_in, const int* in_sizes, int n_in,
                              void* d_out, int out_size, void* d_ws, size_t ws_size,
                              hipStream_t stream) {
    const float* keys    = (const float*)d_in[0];
    const float* queries = (const float*)d_in[1];
    const float* values  = (const float*)d_in[2];
    const float* Wk      = (const float*)d_in[3];
    const float* Wq      = (const float*)d_in[4];
    const float* Wv      = (const float*)d_in[5];
    const int*   key_seq = (const int*)d_in[6];

    const size_t per = (size_t)B_SZ * N_H * T_SZ * D_H;     // 4,194,304 elems
    unsigned short* KQVb = (unsigned short*)d_ws;            // K | Q | V bf16
    unsigned short* Kb = KQVb;
    unsigned short* Qb = KQVb + per;
    unsigned short* Vb = KQVb + 2 * per;
    unsigned short* Wt = KQVb + 3 * per;                     // 3*8*64*512 bf16

    wt_kernel<<<dim3(512 * 512 / 256, 3), 256, 0, stream>>>(Wk, Wq, Wv, Wt);
    proj_kernel<<<dim3((B_SZ * T_SZ) / 128, 3 * N_H), 256, 0, stream>>>(
        keys, queries, values, Wt, KQVb);
    attn_kernel<<<dim3(512), dim3(512), 0, stream>>>(
        Qb, Kb, Vb, key_seq, (float*)d_out);
}

// Round 3
// 156.496 us; speedup vs baseline: 1.1606x; 1.0022x over previous
//
#include <hip/hip_runtime.h>
#include <hip/hip_bf16.h>

#define B_SZ 8
#define T_SZ 1024
#define D_IN 512
#define D_H  64
#define N_H  8

typedef __hip_bfloat16 bf16;
using short8  = __attribute__((ext_vector_type(8))) short;
using short4v = __attribute__((ext_vector_type(4))) short;
using f32x4   = __attribute__((ext_vector_type(4))) float;

__device__ __forceinline__ unsigned short f2bf(float f) {
    union { __hip_bfloat16 b; unsigned short u; } c;
    c.b = __float2bfloat16(f);
    return c.u;
}

// ---------------------------------------------------------------------------
// Weight transpose: W[i(k)][d][h] fp32 -> Wt[mat][c][k] bf16, c = h*64+d.
// grid (512*512/256, 3). Coalesced reads; scattered bf16 writes (L2 absorbs).
// UNCHANGED.
// ---------------------------------------------------------------------------
__global__ __launch_bounds__(256) void wt_kernel(
    const float* __restrict__ Wk, const float* __restrict__ Wq,
    const float* __restrict__ Wv, unsigned short* __restrict__ Wt)
{
    const int mat = blockIdx.y;
    const float* W = (mat == 0) ? Wk : (mat == 1) ? Wq : Wv;
    int idx = blockIdx.x * 256 + threadIdx.x;      // over 512*512
    float v = W[idx];
    int k = idx >> 9, c = idx & 511;               // c = d*8 + h
    int h = c & 7, d = c >> 3;
    Wt[(((size_t)mat * 8 + h) * 64 + d) * 512 + k] = f2bf(v);
}

// ---------------------------------------------------------------------------
// MFMA projection, v2: merged heads -> one GEMM per mat.
//   C[m][c] = sum_k X[m][k] * Wt[mat][c][k],  M=8192, N=512, K=512.
//   grid (64, 4, 3): 128x128 tile, 256 thr = 4 waves (2x2), wave = 64x64
//   (acc[4][4] f32x4, m93 decomposition). K staged in 8 chunks of 64.
//   vs v1: removes the 8x-redundant per-head X stage+convert; 32 MFMA per
//   wave-K-step against 16 ds_read_b128 (was 16:12).
//   Epilogue scatters c=(h,d) into P[b][h][t][d].
// ---------------------------------------------------------------------------
__global__ __launch_bounds__(256, 3) void proj_kernel(
    const float* __restrict__ keys, const float* __restrict__ queries,
    const float* __restrict__ values,
    const unsigned short* __restrict__ Wt, unsigned short* __restrict__ KQVb)
{
    const int tid = threadIdx.x;
    const int m0  = blockIdx.x * 128;
    const int n0  = blockIdx.y * 128;
    const int mat = blockIdx.z;

    const float* X = (mat == 0) ? keys : (mat == 1) ? queries : values;
    const unsigned short* WT = Wt + (size_t)mat * (512 * 512);   // [c][k]
    unsigned short* P = KQVb + (size_t)mat * ((size_t)B_SZ * N_H * T_SZ * D_H);

    __shared__ __align__(16) unsigned short Xst[128 * 72];
    __shared__ __align__(16) unsigned short Wst[128 * 72];

    const int wid = tid >> 6, lane = tid & 63;
    const int quad = lane >> 4, l15 = lane & 15;
    const int wr = (wid >> 1) * 64, wc = (wid & 1) * 64;   // wave sub-tile

    f32x4 acc[4][4];
    #pragma unroll
    for (int i = 0; i < 4; ++i)
        #pragma unroll
        for (int n = 0; n < 4; ++n) acc[i][n] = (f32x4){0.f, 0.f, 0.f, 0.f};

    const float4* X4 = (const float4*)X;

    for (int kc = 0; kc < 8; ++kc) {
        const int k0 = kc * 64;
        __syncthreads();
        // stage X: 128 rows x 64 k, fp32 -> bf16 (8 float4 / thread)
        #pragma unroll
        for (int q2 = 0; q2 < 8; ++q2) {
            int e = tid + q2 * 256;                 // 0..2047 float4s
            int r = e >> 4, c4 = e & 15;
            float4 v = X4[(size_t)(m0 + r) * (D_IN / 4) + (k0 >> 2) + c4];
            short4v s = {(short)f2bf(v.x), (short)f2bf(v.y),
                         (short)f2bf(v.z), (short)f2bf(v.w)};
            *(short4v*)&Xst[r * 72 + c4 * 4] = s;
        }
        // stage Wt tile: 128 c-rows x 64 k, b128 copies (4 / thread)
        #pragma unroll
        for (int q2 = 0; q2 < 4; ++q2) {
            int e = tid + q2 * 256;                 // 0..1023 short8 units
            int row = e >> 3, ch = e & 7;
            *(short8*)&Wst[row * 72 + ch * 8] =
                *(const short8*)&WT[(size_t)(n0 + row) * 512 + k0 + ch * 8];
        }
        __syncthreads();
        // MFMA: wave computes rows [wr,wr+63] x cols [wc,wc+63]
        #pragma unroll
        for (int ic = 0; ic < 2; ++ic) {
            short8 af[4], bf[4];
            #pragma unroll
            for (int mt = 0; mt < 4; ++mt)
                af[mt] = *(const short8*)&Xst[(wr + mt*16 + l15) * 72 + ic*32 + quad*8];
            #pragma unroll
            for (int nt = 0; nt < 4; ++nt)
                bf[nt] = *(const short8*)&Wst[(wc + nt*16 + l15) * 72 + ic*32 + quad*8];
            #pragma unroll
            for (int mt = 0; mt < 4; ++mt)
                #pragma unroll
                for (int nt = 0; nt < 4; ++nt)
                    acc[mt][nt] = __builtin_amdgcn_mfma_f32_16x16x32_bf16(
                        af[mt], bf[nt], acc[mt][nt], 0, 0, 0);
        }
    }

    // epilogue: row m = m0+wr+mt*16+quad*4+r; col c = n0+wc+nt*16+l15
    #pragma unroll
    for (int mt = 0; mt < 4; ++mt)
        #pragma unroll
        for (int r = 0; r < 4; ++r) {
            int mrow = m0 + wr + mt * 16 + quad * 4 + r;
            int bb = mrow >> 10, t = mrow & 1023;
            #pragma unroll
            for (int nt = 0; nt < 4; ++nt) {
                int c = n0 + wc + nt * 16 + l15;
                int h = c >> 6, d = c & 63;
                P[(((size_t)(bb * N_H + h)) * T_SZ + t) * D_H + d] =
                    f2bf(acc[mt][nt][r]);
            }
        }
}

// ---------------------------------------------------------------------------
// MFMA flash attention, v2b. UNCHANGED from the passing round-2 kernel.
//   grid (512): bid = pair*64 + b*8 + h  (bid%8 == h -> per-XCD K/V L2 reuse)
//   block 512 threads = 8 waves: waves 0-3 own j-strip (15-pair)*64 (long),
//   waves 4-7 own j-strip pair*64 (short) -> every block = 17 tile-units.
// ---------------------------------------------------------------------------
#define SCALE  0.18033688f      /* (1/sqrt(64)) * log2(e) */
#define MASKV -180.33688f       /* -1000 * SCALE          */

__global__ __launch_bounds__(512, 4) void attn_kernel(
    const unsigned short* __restrict__ Qb, const unsigned short* __restrict__ Kb,
    const unsigned short* __restrict__ Vb,
    const int* __restrict__ key_seq, float* __restrict__ out)
{
    const int tid  = threadIdx.x;
    const int bid  = blockIdx.x;
    const int pair = bid >> 6;              // 0..7
    const int b    = (bid >> 3) & 7;
    const int h    = bid & 7;               // == bid%8 -> XCD id
    const int wid  = tid >> 6, lane = tid & 63;
    const int quad = lane >> 4, l15 = lane & 15;

    __shared__ __align__(16) unsigned short Kst[2][64 * 72];
    __shared__ __align__(16) unsigned short VTst[2][64 * 72];
    __shared__ __align__(16) float spadf[2][64];
    __shared__ int tflags[16];

    const size_t bh = (size_t)(b * N_H + h) * T_SZ;

    // strip assignment: waves 0-3 -> long strip, waves 4-7 -> short strip
    const int strip_j0 = (wid < 4) ? (15 - pair) * 64 : pair * 64;
    const int j0w = strip_j0 + (wid & 3) * 16;
    const int jg  = j0w + l15;
    const int ntmax = 16 - pair;            // long strip needs tiles 0..ntmax-1

    // Q fragments straight from global (one-time; no LDS staging)
    short8 qf0 = *(const short8*)&Qb[(bh + jg) * D_H + quad * 8];
    short8 qf1 = *(const short8*)&Qb[(bh + jg) * D_H + 32 + quad * 8];

    // per-tile flags: bit0 = any valid key, bit1 = any padded key
    {
        int ka  = key_seq[b * T_SZ + wid * 64 + lane];
        int kb2 = key_seq[b * T_SZ + 512 + wid * 64 + lane];
        unsigned long long ba  = __ballot(ka  != -1);
        unsigned long long bb2 = __ballot(kb2 != -1);
        if (lane == 0) {
            tflags[wid]     = (ba  != 0ull ? 1 : 0) | (ba  != ~0ull ? 2 : 0);
            tflags[8 + wid] = (bb2 != 0ull ? 1 : 0) | (bb2 != ~0ull ? 2 : 0);
        }
    }

    // staging coordinates
    const int sk_row = tid >> 3, sk_c = tid & 7;        // K: 64 rows x 8 chunks
    const int sv_i = lane, sv_ch = wid;                  // V: col i, d-chunk ch
    // permuted V^T column: c = i3*16 + i2*8 + i4*4 + i1i0 (+ i5) so that the
    // MFMA contraction order equals the p[] register order
    const int sv_col = (sv_i & 3) | ((sv_i & 16) >> 2) | ((sv_i & 4) << 1)
                     | ((sv_i & 8) << 1) | (sv_i & 32);

    // issue tile-0 loads
    short8 kreg = *(const short8*)&Kb[(bh + sk_row) * D_H + sk_c * 8];
    short8 vreg = *(const short8*)&Vb[(bh + sv_i) * D_H + sv_ch * 8];
    int ksv = (tid < 64) ? key_seq[b * T_SZ + tid] : -1;

    __syncthreads();                        // tflags ready

    unsigned tmask = 1u, pmask = 0u;
    #pragma unroll
    for (int t = 0; t < 16; ++t) {
        int f = tflags[t];
        tmask |= (unsigned)(f & 1) << t;
        pmask |= (unsigned)((f >> 1) & 1) << t;
    }
    tmask &= (unsigned)((1ull << ntmax) - 1ull);
    tmask |= 1u;                            // tile 0 always processed

    // write tile 0 into buffer 0
    *(short8*)&Kst[0][sk_row * 72 + sk_c * 8] = kreg;
    #pragma unroll
    for (int e = 0; e < 8; ++e)
        VTst[0][(sv_ch * 8 + e) * 72 + sv_col] = (unsigned short)vreg[e];
    if (tid < 64) spadf[0][tid] = (ksv == -1) ? MASKV : 0.f;
    __syncthreads();

    float m = -1e30f, l = 0.f;
    f32x4 o0 = {0.f,0.f,0.f,0.f}, o1 = o0, o2 = o0, o3 = o0;

    unsigned rem = tmask & ~1u;
    int tcur = 0, nb = 0;
    for (;;) {
        // ---- issue next tile's global loads (latency hides under compute) ----
        int tnext = -1;
        if (rem) { tnext = __ffs((int)rem) - 1; rem &= rem - 1; }
        if (tnext >= 0) {
            const size_t r0 = bh + tnext * 64;
            kreg = *(const short8*)&Kb[(r0 + sk_row) * D_H + sk_c * 8];
            vreg = *(const short8*)&Vb[(r0 + sv_i) * D_H + sv_ch * 8];
            if (tid < 64) ksv = key_seq[b * T_SZ + tnext * 64 + tid];
        }

        // ---- compute tile tcur from buffer nb ----
        const int i0 = tcur * 64;
        if (i0 <= j0w + 15) {                           // wave has unmasked rows
            const bool haspad = (pmask >> tcur) & 1u;
            const bool needC  = (i0 + 63 > j0w);        // diagonal tile only
            float sv[16];
            #pragma unroll
            for (int it = 0; it < 4; ++it) {
                f32x4 s = {0.f,0.f,0.f,0.f};
                short8 a0 = *(const short8*)&Kst[nb][(it*16 + l15) * 72 + quad*8];
                s = __builtin_amdgcn_mfma_f32_16x16x32_bf16(a0, qf0, s, 0, 0, 0);
                short8 a1 = *(const short8*)&Kst[nb][(it*16 + l15) * 72 + 32 + quad*8];
                s = __builtin_amdgcn_mfma_f32_16x16x32_bf16(a1, qf1, s, 0, 0, 0);
                f32x4 sp = {0.f,0.f,0.f,0.f};
                if (haspad) sp = *(const f32x4*)&spadf[nb][it*16 + quad*4];
                #pragma unroll
                for (int r = 0; r < 4; ++r) {
                    float v = __builtin_fmaf(s[r], SCALE, sp[r]);
                    if (needC && (i0 + it*16 + quad*4 + r > jg)) v += MASKV;
                    sv[it*4 + r] = v;
                }
            }

            // online softmax over i (per j = l15; i spans regs + quads)
            float mt = sv[0];
            #pragma unroll
            for (int k = 1; k < 16; ++k) mt = fmaxf(mt, sv[k]);
            mt = fmaxf(mt, __shfl_xor(mt, 16));
            mt = fmaxf(mt, __shfl_xor(mt, 32));
            const float mnew  = fmaxf(m, mt);
            const float alpha = exp2f(m - mnew);
            float p[16], ls = 0.f;
            #pragma unroll
            for (int k = 0; k < 16; ++k) {
                p[k] = exp2f(sv[k] - mnew);
                ls += p[k];
            }
            ls += __shfl_xor(ls, 16);
            ls += __shfl_xor(ls, 32);
            l = l * alpha + ls;
            m = mnew;
            o0 *= alpha; o1 *= alpha; o2 *= alpha; o3 *= alpha;

            // PV B-frags directly from registers (V columns pre-permuted)
            short8 pf0, pf1;
            #pragma unroll
            for (int e = 0; e < 8; ++e) {
                pf0[e] = (short)f2bf(p[e]);
                pf1[e] = (short)f2bf(p[8 + e]);
            }
            short8 a;
            a = *(const short8*)&VTst[nb][(     l15) * 72 +      quad * 8];
            o0 = __builtin_amdgcn_mfma_f32_16x16x32_bf16(a, pf0, o0, 0, 0, 0);
            a = *(const short8*)&VTst[nb][(     l15) * 72 + 32 + quad * 8];
            o0 = __builtin_amdgcn_mfma_f32_16x16x32_bf16(a, pf1, o0, 0, 0, 0);
            a = *(const short8*)&VTst[nb][(16 + l15) * 72 +      quad * 8];
            o1 = __builtin_amdgcn_mfma_f32_16x16x32_bf16(a, pf0, o1, 0, 0, 0);
            a = *(const short8*)&VTst[nb][(16 + l15) * 72 + 32 + quad * 8];
            o1 = __builtin_amdgcn_mfma_f32_16x16x32_bf16(a, pf1, o1, 0, 0, 0);
            a = *(const short8*)&VTst[nb][(32 + l15) * 72 +      quad * 8];
            o2 = __builtin_amdgcn_mfma_f32_16x16x32_bf16(a, pf0, o2, 0, 0, 0);
            a = *(const short8*)&VTst[nb][(32 + l15) * 72 + 32 + quad * 8];
            o2 = __builtin_amdgcn_mfma_f32_16x16x32_bf16(a, pf1, o2, 0, 0, 0);
            a = *(const short8*)&VTst[nb][(48 + l15) * 72 +      quad * 8];
            o3 = __builtin_amdgcn_mfma_f32_16x16x32_bf16(a, pf0, o3, 0, 0, 0);
            a = *(const short8*)&VTst[nb][(48 + l15) * 72 + 32 + quad * 8];
            o3 = __builtin_amdgcn_mfma_f32_16x16x32_bf16(a, pf1, o3, 0, 0, 0);
        }

        if (tnext < 0) break;

        // ---- write next tile into the other buffer (T14 late-write) ----
        const int nb2 = nb ^ 1;
        *(short8*)&Kst[nb2][sk_row * 72 + sk_c * 8] = kreg;
        #pragma unroll
        for (int e = 0; e < 8; ++e)
            VTst[nb2][(sv_ch * 8 + e) * 72 + sv_col] = (unsigned short)vreg[e];
        if (tid < 64) spadf[nb2][tid] = (ksv == -1) ? MASKV : 0.f;
        __syncthreads();                     // single barrier per tile
        tcur = tnext; nb = nb2;
    }

    // epilogue: lane j = jg, d = dblk*16 + quad*4 + r -> float4 stores
    const float inv = 1.f / l;
    float* op = out + ((size_t)b * T_SZ + jg) * (N_H * D_H) + h * D_H + quad * 4;
    *(f32x4*)(op +  0) = o0 * inv;
    *(f32x4*)(op + 16) = o1 * inv;
    *(f32x4*)(op + 32) = o2 * inv;
    *(f32x4*)(op + 48) = o3 * inv;
}

// ---------------------------------------------------------------------------
extern "C" void kernel_launch(void* const* d_in, const int* in_sizes, int n_in,
                              void* d_out, int out_size, void* d_ws, size_t ws_size,
                              hipStream_t stream) {
    const float* keys    = (const float*)d_in[0];
    const float* queries = (const float*)d_in[1];
    const float* values  = (const float*)d_in[2];
    const float* Wk      = (const float*)d_in[3];
    const float* Wq      = (const float*)d_in[4];
    const float* Wv      = (const float*)d_in[5];
    const int*   key_seq = (const int*)d_in[6];

    const size_t per = (size_t)B_SZ * N_H * T_SZ * D_H;     // 4,194,304 elems
    unsigned short* KQVb = (unsigned short*)d_ws;            // K | Q | V bf16
    unsigned short* Kb = KQVb;
    unsigned short* Qb = KQVb + per;
    unsigned short* Vb = KQVb + 2 * per;
    unsigned short* Wt = KQVb + 3 * per;                     // 3*8*64*512 bf16

    wt_kernel<<<dim3(512 * 512 / 256, 3), 256, 0, stream>>>(Wk, Wq, Wv, Wt);
    proj_kernel<<<dim3(64, 4, 3), 256, 0, stream>>>(
        keys, queries, values, Wt, KQVb);
    attn_kernel<<<dim3(512), dim3(512), 0, stream>>>(
        Qb, Kb, Vb, key_seq, (float*)d_out);
}

// Round 4
// 153.235 us; speedup vs baseline: 1.1853x; 1.0213x over previous
//
#include <hip/hip_runtime.h>
#include <hip/hip_bf16.h>

#define B_SZ 8
#define T_SZ 1024
#define D_IN 512
#define D_H  64
#define N_H  8

typedef __hip_bfloat16 bf16;
using short8  = __attribute__((ext_vector_type(8))) short;
using short4v = __attribute__((ext_vector_type(4))) short;
using f32x4   = __attribute__((ext_vector_type(4))) float;

__device__ __forceinline__ unsigned short f2bf(float f) {
    union { __hip_bfloat16 b; unsigned short u; } c;
    c.b = __float2bfloat16(f);
    return c.u;
}

// global -> LDS direct copy, 16 B per lane. LDS dest = wave-uniform base +
// lane*16 (linear); global src is per-lane.
__device__ __forceinline__ void glds16(const unsigned short* g, unsigned short* l) {
    __builtin_amdgcn_global_load_lds(
        (const __attribute__((address_space(1))) unsigned int*)g,
        (__attribute__((address_space(3))) unsigned int*)l, 16, 0, 0);
}

// ---------------------------------------------------------------------------
// Weight transpose: W[i(k)][d][h] fp32 -> Wt[mat][c][k'] bf16, c = h*64+d,
// with k PRE-SWIZZLED within each 64-chunk: k' = (k&~63)|((k&63)^((c&7)<<3)).
// proj stages Wt with linear global_load_lds and applies the same XOR on its
// frag reads (rule 21: inverse-swizzle source + swizzle on read).
// ---------------------------------------------------------------------------
__global__ __launch_bounds__(256) void wt_kernel(
    const float* __restrict__ Wk, const float* __restrict__ Wq,
    const float* __restrict__ Wv, unsigned short* __restrict__ Wt)
{
    const int mat = blockIdx.y;
    const float* W = (mat == 0) ? Wk : (mat == 1) ? Wq : Wv;
    int idx = blockIdx.x * 256 + threadIdx.x;      // over 512*512
    float v = W[idx];
    int k = idx >> 9, c = idx & 511;               // c = d*8 + h
    int h = c & 7, d = c >> 3;
    int ks = (k & ~63) | ((k & 63) ^ ((d & 7) << 3));
    Wt[(((size_t)mat * 8 + h) * 64 + d) * 512 + ks] = f2bf(v);
}

// ---------------------------------------------------------------------------
// MFMA projection, v3: pipelined staging.
//   C[m][c] = sum_k X[m][k] * Wt[mat][c][k],  M=8192, N=512, K=512.
//   grid (64, 4, 3): 128x128 tile, 4 waves (2x2), wave = 64x64, acc[4][4].
//   Per K-step (BK=64):
//     - W tile: global_load_lds x4/wave into DOUBLE-buffered Wst (16 KB each),
//       next step's glds issued before current MFMA -> in flight across the
//       barrier (raw s_barrier, no vmcnt drain).
//     - X tile: register-prefetched (8 float4/thread issued one step early,
//       AFTER the glds so the compiler's X-reg wait retires the older glds),
//       fp32->bf16 converted and ds_written at step top.
//     - LDS layout linear [128][64] + XOR swizzle (s ^ ((row&7)<<3)) on both
//       X writes and all frag reads -> 2-way banks (free).
//   LDS 48 KB -> 3 blocks/CU.
// ---------------------------------------------------------------------------
__global__ __launch_bounds__(256, 3) void proj_kernel(
    const float* __restrict__ keys, const float* __restrict__ queries,
    const float* __restrict__ values,
    const unsigned short* __restrict__ Wt, unsigned short* __restrict__ KQVb)
{
    const int tid = threadIdx.x;
    const int m0  = blockIdx.x * 128;
    const int n0  = blockIdx.y * 128;
    const int mat = blockIdx.z;

    const float* X = (mat == 0) ? keys : (mat == 1) ? queries : values;
    const unsigned short* WT = Wt + (size_t)mat * (512 * 512);   // [c][k'] swizzled
    unsigned short* P = KQVb + (size_t)mat * ((size_t)B_SZ * N_H * T_SZ * D_H);

    __shared__ __align__(16) unsigned short Xst[128 * 64];
    __shared__ __align__(16) unsigned short Wst[2][128 * 64];

    const int wid = tid >> 6, lane = tid & 63;
    const int quad = lane >> 4, l15 = lane & 15;
    const int wr = (wid >> 1) * 64, wc = (wid & 1) * 64;   // wave sub-tile

    // X staging coords: unit u = tid + q*256 -> row = ur + q*32, chunk uch
    const int ur = tid >> 3, uch = tid & 7;
    // W glds coords: unit = wid*4+q -> rows wid*32+q*8 + (lane>>3), 16B chunk lane&7
    const int wrow  = wid * 32 + (lane >> 3);
    const int wcol8 = (lane & 7) * 8;

    f32x4 acc[4][4];
    #pragma unroll
    for (int i = 0; i < 4; ++i)
        #pragma unroll
        for (int n = 0; n < 4; ++n) acc[i][n] = (f32x4){0.f, 0.f, 0.f, 0.f};

    const float4* X4 = (const float4*)X;

    // ---- prologue: issue step-0 W glds, then step-0 X loads ----
    #pragma unroll
    for (int q = 0; q < 4; ++q)
        glds16(&WT[(size_t)(n0 + wrow + q * 8) * 512 + wcol8],
               &Wst[0][(wid * 4 + q) * 512]);
    float4 xr[4][2];
    #pragma unroll
    for (int q = 0; q < 4; ++q) {
        int r = ur + q * 32;
        xr[q][0] = X4[(size_t)(m0 + r) * 128 + uch * 2];
        xr[q][1] = X4[(size_t)(m0 + r) * 128 + uch * 2 + 1];
    }

    int wb = 0;
    for (int kc = 0; kc < 8; ++kc) {
        // ---- convert + write X (compiler waits xr -> also retires older glds) ----
        #pragma unroll
        for (int q = 0; q < 4; ++q) {
            int r = ur + q * 32;
            float4 a = xr[q][0], b = xr[q][1];
            short8 s8 = {(short)f2bf(a.x), (short)f2bf(a.y),
                         (short)f2bf(a.z), (short)f2bf(a.w),
                         (short)f2bf(b.x), (short)f2bf(b.y),
                         (short)f2bf(b.z), (short)f2bf(b.w)};
            *(short8*)&Xst[r * 64 + ((uch * 8) ^ ((r & 7) << 3))] = s8;
        }
        // ---- prefetch step kc+1: glds first, then X regs ----
        if (kc < 7) {
            const int k0n = (kc + 1) * 64;
            #pragma unroll
            for (int q = 0; q < 4; ++q)
                glds16(&WT[(size_t)(n0 + wrow + q * 8) * 512 + k0n + wcol8],
                       &Wst[wb ^ 1][(wid * 4 + q) * 512]);
            #pragma unroll
            for (int q = 0; q < 4; ++q) {
                int r = ur + q * 32;
                xr[q][0] = X4[(size_t)(m0 + r) * 128 + (k0n >> 2) + uch * 2];
                xr[q][1] = X4[(size_t)(m0 + r) * 128 + (k0n >> 2) + uch * 2 + 1];
            }
        }
        // ---- barrier 1: LDS writes visible; prefetch stays in flight ----
        asm volatile("s_waitcnt lgkmcnt(0)" ::: "memory");
        __builtin_amdgcn_s_barrier();

        // ---- MFMA on Xst / Wst[wb] ----
        #pragma unroll
        for (int ic = 0; ic < 2; ++ic) {
            const int sc = ic * 32 + quad * 8;
            short8 af[4], bfr[4];
            #pragma unroll
            for (int mt = 0; mt < 4; ++mt) {
                int r = wr + mt * 16 + l15;
                af[mt] = *(const short8*)&Xst[r * 64 + (sc ^ ((r & 7) << 3))];
            }
            #pragma unroll
            for (int nt = 0; nt < 4; ++nt) {
                int r = wc + nt * 16 + l15;
                bfr[nt] = *(const short8*)&Wst[wb][r * 64 + (sc ^ ((r & 7) << 3))];
            }
            #pragma unroll
            for (int mt = 0; mt < 4; ++mt)
                #pragma unroll
                for (int nt = 0; nt < 4; ++nt)
                    acc[mt][nt] = __builtin_amdgcn_mfma_f32_16x16x32_bf16(
                        af[mt], bfr[nt], acc[mt][nt], 0, 0, 0);
        }

        // ---- barrier 2: frag reads retired before next step's X overwrite ----
        asm volatile("s_waitcnt lgkmcnt(0)" ::: "memory");
        __builtin_amdgcn_s_barrier();
        wb ^= 1;
    }

    // epilogue: row m = m0+wr+mt*16+quad*4+r; col c = n0+wc+nt*16+l15
    #pragma unroll
    for (int mt = 0; mt < 4; ++mt)
        #pragma unroll
        for (int r = 0; r < 4; ++r) {
            int mrow = m0 + wr + mt * 16 + quad * 4 + r;
            int bb = mrow >> 10, t = mrow & 1023;
            #pragma unroll
            for (int nt = 0; nt < 4; ++nt) {
                int c = n0 + wc + nt * 16 + l15;
                int h = c >> 6, d = c & 63;
                P[(((size_t)(bb * N_H + h)) * T_SZ + t) * D_H + d] =
                    f2bf(acc[mt][nt][r]);
            }
        }
}

// ---------------------------------------------------------------------------
// MFMA flash attention, v2b. UNCHANGED from the passing round-2 kernel.
// ---------------------------------------------------------------------------
#define SCALE  0.18033688f      /* (1/sqrt(64)) * log2(e) */
#define MASKV -180.33688f       /* -1000 * SCALE          */

__global__ __launch_bounds__(512, 4) void attn_kernel(
    const unsigned short* __restrict__ Qb, const unsigned short* __restrict__ Kb,
    const unsigned short* __restrict__ Vb,
    const int* __restrict__ key_seq, float* __restrict__ out)
{
    const int tid  = threadIdx.x;
    const int bid  = blockIdx.x;
    const int pair = bid >> 6;              // 0..7
    const int b    = (bid >> 3) & 7;
    const int h    = bid & 7;               // == bid%8 -> XCD id
    const int wid  = tid >> 6, lane = tid & 63;
    const int quad = lane >> 4, l15 = lane & 15;

    __shared__ __align__(16) unsigned short Kst[2][64 * 72];
    __shared__ __align__(16) unsigned short VTst[2][64 * 72];
    __shared__ __align__(16) float spadf[2][64];
    __shared__ int tflags[16];

    const size_t bh = (size_t)(b * N_H + h) * T_SZ;

    // strip assignment: waves 0-3 -> long strip, waves 4-7 -> short strip
    const int strip_j0 = (wid < 4) ? (15 - pair) * 64 : pair * 64;
    const int j0w = strip_j0 + (wid & 3) * 16;
    const int jg  = j0w + l15;
    const int ntmax = 16 - pair;            // long strip needs tiles 0..ntmax-1

    // Q fragments straight from global (one-time; no LDS staging)
    short8 qf0 = *(const short8*)&Qb[(bh + jg) * D_H + quad * 8];
    short8 qf1 = *(const short8*)&Qb[(bh + jg) * D_H + 32 + quad * 8];

    // per-tile flags: bit0 = any valid key, bit1 = any padded key
    {
        int ka  = key_seq[b * T_SZ + wid * 64 + lane];
        int kb2 = key_seq[b * T_SZ + 512 + wid * 64 + lane];
        unsigned long long ba  = __ballot(ka  != -1);
        unsigned long long bb2 = __ballot(kb2 != -1);
        if (lane == 0) {
            tflags[wid]     = (ba  != 0ull ? 1 : 0) | (ba  != ~0ull ? 2 : 0);
            tflags[8 + wid] = (bb2 != 0ull ? 1 : 0) | (bb2 != ~0ull ? 2 : 0);
        }
    }

    // staging coordinates
    const int sk_row = tid >> 3, sk_c = tid & 7;        // K: 64 rows x 8 chunks
    const int sv_i = lane, sv_ch = wid;                  // V: col i, d-chunk ch
    // permuted V^T column: c = i3*16 + i2*8 + i4*4 + i1i0 (+ i5) so that the
    // MFMA contraction order equals the p[] register order
    const int sv_col = (sv_i & 3) | ((sv_i & 16) >> 2) | ((sv_i & 4) << 1)
                     | ((sv_i & 8) << 1) | (sv_i & 32);

    // issue tile-0 loads
    short8 kreg = *(const short8*)&Kb[(bh + sk_row) * D_H + sk_c * 8];
    short8 vreg = *(const short8*)&Vb[(bh + sv_i) * D_H + sv_ch * 8];
    int ksv = (tid < 64) ? key_seq[b * T_SZ + tid] : -1;

    __syncthreads();                        // tflags ready

    unsigned tmask = 1u, pmask = 0u;
    #pragma unroll
    for (int t = 0; t < 16; ++t) {
        int f = tflags[t];
        tmask |= (unsigned)(f & 1) << t;
        pmask |= (unsigned)((f >> 1) & 1) << t;
    }
    tmask &= (unsigned)((1ull << ntmax) - 1ull);
    tmask |= 1u;                            // tile 0 always processed

    // write tile 0 into buffer 0
    *(short8*)&Kst[0][sk_row * 72 + sk_c * 8] = kreg;
    #pragma unroll
    for (int e = 0; e < 8; ++e)
        VTst[0][(sv_ch * 8 + e) * 72 + sv_col] = (unsigned short)vreg[e];
    if (tid < 64) spadf[0][tid] = (ksv == -1) ? MASKV : 0.f;
    __syncthreads();

    float m = -1e30f, l = 0.f;
    f32x4 o0 = {0.f,0.f,0.f,0.f}, o1 = o0, o2 = o0, o3 = o0;

    unsigned rem = tmask & ~1u;
    int tcur = 0, nb = 0;
    for (;;) {
        // ---- issue next tile's global loads (latency hides under compute) ----
        int tnext = -1;
        if (rem) { tnext = __ffs((int)rem) - 1; rem &= rem - 1; }
        if (tnext >= 0) {
            const size_t r0 = bh + tnext * 64;
            kreg = *(const short8*)&Kb[(r0 + sk_row) * D_H + sk_c * 8];
            vreg = *(const short8*)&Vb[(r0 + sv_i) * D_H + sv_ch * 8];
            if (tid < 64) ksv = key_seq[b * T_SZ + tnext * 64 + tid];
        }

        // ---- compute tile tcur from buffer nb ----
        const int i0 = tcur * 64;
        if (i0 <= j0w + 15) {                           // wave has unmasked rows
            const bool haspad = (pmask >> tcur) & 1u;
            const bool needC  = (i0 + 63 > j0w);        // diagonal tile only
            float sv[16];
            #pragma unroll
            for (int it = 0; it < 4; ++it) {
                f32x4 s = {0.f,0.f,0.f,0.f};
                short8 a0 = *(const short8*)&Kst[nb][(it*16 + l15) * 72 + quad*8];
                s = __builtin_amdgcn_mfma_f32_16x16x32_bf16(a0, qf0, s, 0, 0, 0);
                short8 a1 = *(const short8*)&Kst[nb][(it*16 + l15) * 72 + 32 + quad*8];
                s = __builtin_amdgcn_mfma_f32_16x16x32_bf16(a1, qf1, s, 0, 0, 0);
                f32x4 sp = {0.f,0.f,0.f,0.f};
                if (haspad) sp = *(const f32x4*)&spadf[nb][it*16 + quad*4];
                #pragma unroll
                for (int r = 0; r < 4; ++r) {
                    float v = __builtin_fmaf(s[r], SCALE, sp[r]);
                    if (needC && (i0 + it*16 + quad*4 + r > jg)) v += MASKV;
                    sv[it*4 + r] = v;
                }
            }

            // online softmax over i (per j = l15; i spans regs + quads)
            float mt = sv[0];
            #pragma unroll
            for (int k = 1; k < 16; ++k) mt = fmaxf(mt, sv[k]);
            mt = fmaxf(mt, __shfl_xor(mt, 16));
            mt = fmaxf(mt, __shfl_xor(mt, 32));
            const float mnew  = fmaxf(m, mt);
            const float alpha = exp2f(m - mnew);
            float p[16], ls = 0.f;
            #pragma unroll
            for (int k = 0; k < 16; ++k) {
                p[k] = exp2f(sv[k] - mnew);
                ls += p[k];
            }
            ls += __shfl_xor(ls, 16);
            ls += __shfl_xor(ls, 32);
            l = l * alpha + ls;
            m = mnew;
            o0 *= alpha; o1 *= alpha; o2 *= alpha; o3 *= alpha;

            // PV B-frags directly from registers (V columns pre-permuted)
            short8 pf0, pf1;
            #pragma unroll
            for (int e = 0; e < 8; ++e) {
                pf0[e] = (short)f2bf(p[e]);
                pf1[e] = (short)f2bf(p[8 + e]);
            }
            short8 a;
            a = *(const short8*)&VTst[nb][(     l15) * 72 +      quad * 8];
            o0 = __builtin_amdgcn_mfma_f32_16x16x32_bf16(a, pf0, o0, 0, 0, 0);
            a = *(const short8*)&VTst[nb][(     l15) * 72 + 32 + quad * 8];
            o0 = __builtin_amdgcn_mfma_f32_16x16x32_bf16(a, pf1, o0, 0, 0, 0);
            a = *(const short8*)&VTst[nb][(16 + l15) * 72 +      quad * 8];
            o1 = __builtin_amdgcn_mfma_f32_16x16x32_bf16(a, pf0, o1, 0, 0, 0);
            a = *(const short8*)&VTst[nb][(16 + l15) * 72 + 32 + quad * 8];
            o1 = __builtin_amdgcn_mfma_f32_16x16x32_bf16(a, pf1, o1, 0, 0, 0);
            a = *(const short8*)&VTst[nb][(32 + l15) * 72 +      quad * 8];
            o2 = __builtin_amdgcn_mfma_f32_16x16x32_bf16(a, pf0, o2, 0, 0, 0);
            a = *(const short8*)&VTst[nb][(32 + l15) * 72 + 32 + quad * 8];
            o2 = __builtin_amdgcn_mfma_f32_16x16x32_bf16(a, pf1, o2, 0, 0, 0);
            a = *(const short8*)&VTst[nb][(48 + l15) * 72 +      quad * 8];
            o3 = __builtin_amdgcn_mfma_f32_16x16x32_bf16(a, pf0, o3, 0, 0, 0);
            a = *(const short8*)&VTst[nb][(48 + l15) * 72 + 32 + quad * 8];
            o3 = __builtin_amdgcn_mfma_f32_16x16x32_bf16(a, pf1, o3, 0, 0, 0);
        }

        if (tnext < 0) break;

        // ---- write next tile into the other buffer (T14 late-write) ----
        const int nb2 = nb ^ 1;
        *(short8*)&Kst[nb2][sk_row * 72 + sk_c * 8] = kreg;
        #pragma unroll
        for (int e = 0; e < 8; ++e)
            VTst[nb2][(sv_ch * 8 + e) * 72 + sv_col] = (unsigned short)vreg[e];
        if (tid < 64) spadf[nb2][tid] = (ksv == -1) ? MASKV : 0.f;
        __syncthreads();                     // single barrier per tile
        tcur = tnext; nb = nb2;
    }

    // epilogue: lane j = jg, d = dblk*16 + quad*4 + r -> float4 stores
    const float inv = 1.f / l;
    float* op = out + ((size_t)b * T_SZ + jg) * (N_H * D_H) + h * D_H + quad * 4;
    *(f32x4*)(op +  0) = o0 * inv;
    *(f32x4*)(op + 16) = o1 * inv;
    *(f32x4*)(op + 32) = o2 * inv;
    *(f32x4*)(op + 48) = o3 * inv;
}

// ---------------------------------------------------------------------------
extern "C" void kernel_launch(void* const* d_in, const int* in_sizes, int n_in,
                              void* d_out, int out_size, void* d_ws, size_t ws_size,
                              hipStream_t stream) {
    const float* keys    = (const float*)d_in[0];
    const float* queries = (const float*)d_in[1];
    const float* values  = (const float*)d_in[2];
    const float* Wk      = (const float*)d_in[3];
    const float* Wq      = (const float*)d_in[4];
    const float* Wv      = (const float*)d_in[5];
    const int*   key_seq = (const int*)d_in[6];

    const size_t per = (size_t)B_SZ * N_H * T_SZ * D_H;     // 4,194,304 elems
    unsigned short* KQVb = (unsigned short*)d_ws;            // K | Q | V bf16
    unsigned short* Kb = KQVb;
    unsigned short* Qb = KQVb + per;
    unsigned short* Vb = KQVb + 2 * per;
    unsigned short* Wt = KQVb + 3 * per;                     // 3*8*64*512 bf16

    wt_kernel<<<dim3(512 * 512 / 256, 3), 256, 0, stream>>>(Wk, Wq, Wv, Wt);
    proj_kernel<<<dim3(64, 4, 3), 256, 0, stream>>>(
        keys, queries, values, Wt, KQVb);
    attn_kernel<<<dim3(512), dim3(512), 0, stream>>>(
        Qb, Kb, Vb, key_seq, (float*)d_out);
}

// Round 6
// 152.103 us; speedup vs baseline: 1.1941x; 1.0074x over previous
//
#include <hip/hip_runtime.h>
#include <hip/hip_bf16.h>

#define B_SZ 8
#define T_SZ 1024
#define D_IN 512
#define D_H  64
#define N_H  8

typedef __hip_bfloat16 bf16;
using short8  = __attribute__((ext_vector_type(8))) short;
using short4v = __attribute__((ext_vector_type(4))) short;
using f32x4   = __attribute__((ext_vector_type(4))) float;

__device__ __forceinline__ unsigned short f2bf(float f) {
    union { __hip_bfloat16 b; unsigned short u; } c;
    c.b = __float2bfloat16(f);
    return c.u;
}

// global -> LDS direct copy, 16 B per lane. LDS dest = wave-uniform base +
// lane*16 (linear); global src is per-lane.
__device__ __forceinline__ void glds16(const unsigned short* g, unsigned short* l) {
    __builtin_amdgcn_global_load_lds(
        (const __attribute__((address_space(1))) unsigned int*)g,
        (__attribute__((address_space(3))) unsigned int*)l, 16, 0, 0);
}

// ---------------------------------------------------------------------------
// Weight transpose: W[i(k)][d][h] fp32 -> Wt[mat][c][k'] bf16, c = h*64+d,
// with k PRE-SWIZZLED within each 64-chunk: k' = (k&~63)|((k&63)^((c&7)<<3)).
// proj stages Wt with linear global_load_lds and applies the same XOR on its
// frag reads (rule 21: inverse-swizzle source + swizzle on read). UNCHANGED.
// ---------------------------------------------------------------------------
__global__ __launch_bounds__(256) void wt_kernel(
    const float* __restrict__ Wk, const float* __restrict__ Wq,
    const float* __restrict__ Wv, unsigned short* __restrict__ Wt)
{
    const int mat = blockIdx.y;
    const float* W = (mat == 0) ? Wk : (mat == 1) ? Wq : Wv;
    int idx = blockIdx.x * 256 + threadIdx.x;      // over 512*512
    float v = W[idx];
    int k = idx >> 9, c = idx & 511;               // c = d*8 + h
    int h = c & 7, d = c >> 3;
    int ks = (k & ~63) | ((k & 63) ^ ((d & 7) << 3));
    Wt[(((size_t)mat * 8 + h) * 64 + d) * 512 + ks] = f2bf(v);
}

// ---------------------------------------------------------------------------
// MFMA projection, v4: counted-vmcnt pipeline (T4).
//   Issue order per step: [X8 loads][sched_bar][G4 glds][sched_bar] so the
//   X-convert's implicit wait retires ONLY the X loads (in-order FIFO), and
//   the explicit s_waitcnt vmcnt(12) before barrier1 waits ONLY for this
//   step's W glds -- next step's 12 VMEM ops stay in flight across the
//   barrier. Last step waits vmcnt(0).
//   Geometry unchanged: 128x128 tile, 4 waves 2x2, acc[4][4], BK=64,
//   Xst single + Wst double, XOR-swizzled LDS, 48 KB, 3 blocks/CU.
// ---------------------------------------------------------------------------
__global__ __launch_bounds__(256, 3) void proj_kernel(
    const float* __restrict__ keys, const float* __restrict__ queries,
    const float* __restrict__ values,
    const unsigned short* __restrict__ Wt, unsigned short* __restrict__ KQVb)
{
    const int tid = threadIdx.x;
    const int m0  = blockIdx.x * 128;
    const int n0  = blockIdx.y * 128;
    const int mat = blockIdx.z;

    const float* X = (mat == 0) ? keys : (mat == 1) ? queries : values;
    const unsigned short* WT = Wt + (size_t)mat * (512 * 512);   // [c][k'] swizzled
    unsigned short* P = KQVb + (size_t)mat * ((size_t)B_SZ * N_H * T_SZ * D_H);

    __shared__ __align__(16) unsigned short Xst[128 * 64];
    __shared__ __align__(16) unsigned short Wst[2][128 * 64];

    const int wid = tid >> 6, lane = tid & 63;
    const int quad = lane >> 4, l15 = lane & 15;
    const int wr = (wid >> 1) * 64, wc = (wid & 1) * 64;   // wave sub-tile

    // X staging coords: unit u = tid + q*256 -> row = ur + q*32, chunk uch
    const int ur = tid >> 3, uch = tid & 7;
    // W glds coords: unit = wid*4+q -> rows wid*32+q*8 + (lane>>3), 16B chunk lane&7
    const int wrow  = wid * 32 + (lane >> 3);
    const int wcol8 = (lane & 7) * 8;

    f32x4 acc[4][4];
    #pragma unroll
    for (int i = 0; i < 4; ++i)
        #pragma unroll
        for (int n = 0; n < 4; ++n) acc[i][n] = (f32x4){0.f, 0.f, 0.f, 0.f};

    const float4* X4 = (const float4*)X;

    // ---- prologue: X loads FIRST, glds SECOND (FIFO order matters) ----
    float4 xr[4][2];
    #pragma unroll
    for (int q = 0; q < 4; ++q) {
        int r = ur + q * 32;
        xr[q][0] = X4[(size_t)(m0 + r) * 128 + uch * 2];
        xr[q][1] = X4[(size_t)(m0 + r) * 128 + uch * 2 + 1];
    }
    __builtin_amdgcn_sched_barrier(0);
    #pragma unroll
    for (int q = 0; q < 4; ++q)
        glds16(&WT[(size_t)(n0 + wrow + q * 8) * 512 + wcol8],
               &Wst[0][(wid * 4 + q) * 512]);
    __builtin_amdgcn_sched_barrier(0);

    int wb = 0;
    for (int kc = 0; kc < 8; ++kc) {
        // ---- convert + write X: implicit wait retires X8(kc) only; the
        //      G4(kc) glds (younger in FIFO) stay outstanding ----
        #pragma unroll
        for (int q = 0; q < 4; ++q) {
            int r = ur + q * 32;
            float4 a = xr[q][0], b = xr[q][1];
            short8 s8 = {(short)f2bf(a.x), (short)f2bf(a.y),
                         (short)f2bf(a.z), (short)f2bf(a.w),
                         (short)f2bf(b.x), (short)f2bf(b.y),
                         (short)f2bf(b.z), (short)f2bf(b.w)};
            *(short8*)&Xst[r * 64 + ((uch * 8) ^ ((r & 7) << 3))] = s8;
        }
        // ---- prefetch step kc+1: X8 then G4, then counted wait for G4(kc) ----
        if (kc < 7) {
            const int k0n = (kc + 1) * 64;
            #pragma unroll
            for (int q = 0; q < 4; ++q) {
                int r = ur + q * 32;
                xr[q][0] = X4[(size_t)(m0 + r) * 128 + (k0n >> 2) + uch * 2];
                xr[q][1] = X4[(size_t)(m0 + r) * 128 + (k0n >> 2) + uch * 2 + 1];
            }
            __builtin_amdgcn_sched_barrier(0);
            #pragma unroll
            for (int q = 0; q < 4; ++q)
                glds16(&WT[(size_t)(n0 + wrow + q * 8) * 512 + k0n + wcol8],
                       &Wst[wb ^ 1][(wid * 4 + q) * 512]);
            __builtin_amdgcn_sched_barrier(0);
            // outstanding: G4(kc) + X8(kc+1) + G4(kc+1) = 16; keep 12 youngest
            asm volatile("s_waitcnt vmcnt(12)" ::: "memory");
        } else {
            asm volatile("s_waitcnt vmcnt(0)" ::: "memory");
        }
        __builtin_amdgcn_sched_barrier(0);
        // ---- barrier 1: LDS writes visible; prefetch stays in flight ----
        asm volatile("s_waitcnt lgkmcnt(0)" ::: "memory");
        __builtin_amdgcn_s_barrier();

        // ---- MFMA on Xst / Wst[wb] ----
        #pragma unroll
        for (int ic = 0; ic < 2; ++ic) {
            const int sc = ic * 32 + quad * 8;
            short8 af[4], bfr[4];
            #pragma unroll
            for (int mt = 0; mt < 4; ++mt) {
                int r = wr + mt * 16 + l15;
                af[mt] = *(const short8*)&Xst[r * 64 + (sc ^ ((r & 7) << 3))];
            }
            #pragma unroll
            for (int nt = 0; nt < 4; ++nt) {
                int r = wc + nt * 16 + l15;
                bfr[nt] = *(const short8*)&Wst[wb][r * 64 + (sc ^ ((r & 7) << 3))];
            }
            #pragma unroll
            for (int mt = 0; mt < 4; ++mt)
                #pragma unroll
                for (int nt = 0; nt < 4; ++nt)
                    acc[mt][nt] = __builtin_amdgcn_mfma_f32_16x16x32_bf16(
                        af[mt], bfr[nt], acc[mt][nt], 0, 0, 0);
        }

        // ---- barrier 2: frag reads retired before next step's X overwrite ----
        asm volatile("s_waitcnt lgkmcnt(0)" ::: "memory");
        __builtin_amdgcn_s_barrier();
        wb ^= 1;
    }

    // epilogue: row m = m0+wr+mt*16+quad*4+r; col c = n0+wc+nt*16+l15
    #pragma unroll
    for (int mt = 0; mt < 4; ++mt)
        #pragma unroll
        for (int r = 0; r < 4; ++r) {
            int mrow = m0 + wr + mt * 16 + quad * 4 + r;
            int bb = mrow >> 10, t = mrow & 1023;
            #pragma unroll
            for (int nt = 0; nt < 4; ++nt) {
                int c = n0 + wc + nt * 16 + l15;
                int h = c >> 6, d = c & 63;
                P[(((size_t)(bb * N_H + h)) * T_SZ + t) * D_H + d] =
                    f2bf(acc[mt][nt][r]);
            }
        }
}

// ---------------------------------------------------------------------------
// MFMA flash attention, v2b. EXACT text of the round-4 passing kernel
// (setprio removed again -- bisection: isolate proj's counted-vmcnt change).
// ---------------------------------------------------------------------------
#define SCALE  0.18033688f      /* (1/sqrt(64)) * log2(e) */
#define MASKV -180.33688f       /* -1000 * SCALE          */

__global__ __launch_bounds__(512, 4) void attn_kernel(
    const unsigned short* __restrict__ Qb, const unsigned short* __restrict__ Kb,
    const unsigned short* __restrict__ Vb,
    const int* __restrict__ key_seq, float* __restrict__ out)
{
    const int tid  = threadIdx.x;
    const int bid  = blockIdx.x;
    const int pair = bid >> 6;              // 0..7
    const int b    = (bid >> 3) & 7;
    const int h    = bid & 7;               // == bid%8 -> XCD id
    const int wid  = tid >> 6, lane = tid & 63;
    const int quad = lane >> 4, l15 = lane & 15;

    __shared__ __align__(16) unsigned short Kst[2][64 * 72];
    __shared__ __align__(16) unsigned short VTst[2][64 * 72];
    __shared__ __align__(16) float spadf[2][64];
    __shared__ int tflags[16];

    const size_t bh = (size_t)(b * N_H + h) * T_SZ;

    // strip assignment: waves 0-3 -> long strip, waves 4-7 -> short strip
    const int strip_j0 = (wid < 4) ? (15 - pair) * 64 : pair * 64;
    const int j0w = strip_j0 + (wid & 3) * 16;
    const int jg  = j0w + l15;
    const int ntmax = 16 - pair;            // long strip needs tiles 0..ntmax-1

    // Q fragments straight from global (one-time; no LDS staging)
    short8 qf0 = *(const short8*)&Qb[(bh + jg) * D_H + quad * 8];
    short8 qf1 = *(const short8*)&Qb[(bh + jg) * D_H + 32 + quad * 8];

    // per-tile flags: bit0 = any valid key, bit1 = any padded key
    {
        int ka  = key_seq[b * T_SZ + wid * 64 + lane];
        int kb2 = key_seq[b * T_SZ + 512 + wid * 64 + lane];
        unsigned long long ba  = __ballot(ka  != -1);
        unsigned long long bb2 = __ballot(kb2 != -1);
        if (lane == 0) {
            tflags[wid]     = (ba  != 0ull ? 1 : 0) | (ba  != ~0ull ? 2 : 0);
            tflags[8 + wid] = (bb2 != 0ull ? 1 : 0) | (bb2 != ~0ull ? 2 : 0);
        }
    }

    // staging coordinates
    const int sk_row = tid >> 3, sk_c = tid & 7;        // K: 64 rows x 8 chunks
    const int sv_i = lane, sv_ch = wid;                  // V: col i, d-chunk ch
    // permuted V^T column: c = i3*16 + i2*8 + i4*4 + i1i0 (+ i5) so that the
    // MFMA contraction order equals the p[] register order
    const int sv_col = (sv_i & 3) | ((sv_i & 16) >> 2) | ((sv_i & 4) << 1)
                     | ((sv_i & 8) << 1) | (sv_i & 32);

    // issue tile-0 loads
    short8 kreg = *(const short8*)&Kb[(bh + sk_row) * D_H + sk_c * 8];
    short8 vreg = *(const short8*)&Vb[(bh + sv_i) * D_H + sv_ch * 8];
    int ksv = (tid < 64) ? key_seq[b * T_SZ + tid] : -1;

    __syncthreads();                        // tflags ready

    unsigned tmask = 1u, pmask = 0u;
    #pragma unroll
    for (int t = 0; t < 16; ++t) {
        int f = tflags[t];
        tmask |= (unsigned)(f & 1) << t;
        pmask |= (unsigned)((f >> 1) & 1) << t;
    }
    tmask &= (unsigned)((1ull << ntmax) - 1ull);
    tmask |= 1u;                            // tile 0 always processed

    // write tile 0 into buffer 0
    *(short8*)&Kst[0][sk_row * 72 + sk_c * 8] = kreg;
    #pragma unroll
    for (int e = 0; e < 8; ++e)
        VTst[0][(sv_ch * 8 + e) * 72 + sv_col] = (unsigned short)vreg[e];
    if (tid < 64) spadf[0][tid] = (ksv == -1) ? MASKV : 0.f;
    __syncthreads();

    float m = -1e30f, l = 0.f;
    f32x4 o0 = {0.f,0.f,0.f,0.f}, o1 = o0, o2 = o0, o3 = o0;

    unsigned rem = tmask & ~1u;
    int tcur = 0, nb = 0;
    for (;;) {
        // ---- issue next tile's global loads (latency hides under compute) ----
        int tnext = -1;
        if (rem) { tnext = __ffs((int)rem) - 1; rem &= rem - 1; }
        if (tnext >= 0) {
            const size_t r0 = bh + tnext * 64;
            kreg = *(const short8*)&Kb[(r0 + sk_row) * D_H + sk_c * 8];
            vreg = *(const short8*)&Vb[(r0 + sv_i) * D_H + sv_ch * 8];
            if (tid < 64) ksv = key_seq[b * T_SZ + tnext * 64 + tid];
        }

        // ---- compute tile tcur from buffer nb ----
        const int i0 = tcur * 64;
        if (i0 <= j0w + 15) {                           // wave has unmasked rows
            const bool haspad = (pmask >> tcur) & 1u;
            const bool needC  = (i0 + 63 > j0w);        // diagonal tile only
            float sv[16];
            #pragma unroll
            for (int it = 0; it < 4; ++it) {
                f32x4 s = {0.f,0.f,0.f,0.f};
                short8 a0 = *(const short8*)&Kst[nb][(it*16 + l15) * 72 + quad*8];
                s = __builtin_amdgcn_mfma_f32_16x16x32_bf16(a0, qf0, s, 0, 0, 0);
                short8 a1 = *(const short8*)&Kst[nb][(it*16 + l15) * 72 + 32 + quad*8];
                s = __builtin_amdgcn_mfma_f32_16x16x32_bf16(a1, qf1, s, 0, 0, 0);
                f32x4 sp = {0.f,0.f,0.f,0.f};
                if (haspad) sp = *(const f32x4*)&spadf[nb][it*16 + quad*4];
                #pragma unroll
                for (int r = 0; r < 4; ++r) {
                    float v = __builtin_fmaf(s[r], SCALE, sp[r]);
                    if (needC && (i0 + it*16 + quad*4 + r > jg)) v += MASKV;
                    sv[it*4 + r] = v;
                }
            }

            // online softmax over i (per j = l15; i spans regs + quads)
            float mt = sv[0];
            #pragma unroll
            for (int k = 1; k < 16; ++k) mt = fmaxf(mt, sv[k]);
            mt = fmaxf(mt, __shfl_xor(mt, 16));
            mt = fmaxf(mt, __shfl_xor(mt, 32));
            const float mnew  = fmaxf(m, mt);
            const float alpha = exp2f(m - mnew);
            float p[16], ls = 0.f;
            #pragma unroll
            for (int k = 0; k < 16; ++k) {
                p[k] = exp2f(sv[k] - mnew);
                ls += p[k];
            }
            ls += __shfl_xor(ls, 16);
            ls += __shfl_xor(ls, 32);
            l = l * alpha + ls;
            m = mnew;
            o0 *= alpha; o1 *= alpha; o2 *= alpha; o3 *= alpha;

            // PV B-frags directly from registers (V columns pre-permuted)
            short8 pf0, pf1;
            #pragma unroll
            for (int e = 0; e < 8; ++e) {
                pf0[e] = (short)f2bf(p[e]);
                pf1[e] = (short)f2bf(p[8 + e]);
            }
            short8 a;
            a = *(const short8*)&VTst[nb][(     l15) * 72 +      quad * 8];
            o0 = __builtin_amdgcn_mfma_f32_16x16x32_bf16(a, pf0, o0, 0, 0, 0);
            a = *(const short8*)&VTst[nb][(     l15) * 72 + 32 + quad * 8];
            o0 = __builtin_amdgcn_mfma_f32_16x16x32_bf16(a, pf1, o0, 0, 0, 0);
            a = *(const short8*)&VTst[nb][(16 + l15) * 72 +      quad * 8];
            o1 = __builtin_amdgcn_mfma_f32_16x16x32_bf16(a, pf0, o1, 0, 0, 0);
            a = *(const short8*)&VTst[nb][(16 + l15) * 72 + 32 + quad * 8];
            o1 = __builtin_amdgcn_mfma_f32_16x16x32_bf16(a, pf1, o1, 0, 0, 0);
            a = *(const short8*)&VTst[nb][(32 + l15) * 72 +      quad * 8];
            o2 = __builtin_amdgcn_mfma_f32_16x16x32_bf16(a, pf0, o2, 0, 0, 0);
            a = *(const short8*)&VTst[nb][(32 + l15) * 72 + 32 + quad * 8];
            o2 = __builtin_amdgcn_mfma_f32_16x16x32_bf16(a, pf1, o2, 0, 0, 0);
            a = *(const short8*)&VTst[nb][(48 + l15) * 72 +      quad * 8];
            o3 = __builtin_amdgcn_mfma_f32_16x16x32_bf16(a, pf0, o3, 0, 0, 0);
            a = *(const short8*)&VTst[nb][(48 + l15) * 72 + 32 + quad * 8];
            o3 = __builtin_amdgcn_mfma_f32_16x16x32_bf16(a, pf1, o3, 0, 0, 0);
        }

        if (tnext < 0) break;

        // ---- write next tile into the other buffer (T14 late-write) ----
        const int nb2 = nb ^ 1;
        *(short8*)&Kst[nb2][sk_row * 72 + sk_c * 8] = kreg;
        #pragma unroll
        for (int e = 0; e < 8; ++e)
            VTst[nb2][(sv_ch * 8 + e) * 72 + sv_col] = (unsigned short)vreg[e];
        if (tid < 64) spadf[nb2][tid] = (ksv == -1) ? MASKV : 0.f;
        __syncthreads();                     // single barrier per tile
        tcur = tnext; nb = nb2;
    }

    // epilogue: lane j = jg, d = dblk*16 + quad*4 + r -> float4 stores
    const float inv = 1.f / l;
    float* op = out + ((size_t)b * T_SZ + jg) * (N_H * D_H) + h * D_H + quad * 4;
    *(f32x4*)(op +  0) = o0 * inv;
    *(f32x4*)(op + 16) = o1 * inv;
    *(f32x4*)(op + 32) = o2 * inv;
    *(f32x4*)(op + 48) = o3 * inv;
}

// ---------------------------------------------------------------------------
extern "C" void kernel_launch(void* const* d_in, const int* in_sizes, int n_in,
                              void* d_out, int out_size, void* d_ws, size_t ws_size,
                              hipStream_t stream) {
    const float* keys    = (const float*)d_in[0];
    const float* queries = (const float*)d_in[1];
    const float* values  = (const float*)d_in[2];
    const float* Wk      = (const float*)d_in[3];
    const float* Wq      = (const float*)d_in[4];
    const float* Wv      = (const float*)d_in[5];
    const int*   key_seq = (const int*)d_in[6];

    const size_t per = (size_t)B_SZ * N_H * T_SZ * D_H;     // 4,194,304 elems
    unsigned short* KQVb = (unsigned short*)d_ws;            // K | Q | V bf16
    unsigned short* Kb = KQVb;
    unsigned short* Qb = KQVb + per;
    unsigned short* Vb = KQVb + 2 * per;
    unsigned short* Wt = KQVb + 3 * per;                     // 3*8*64*512 bf16

    wt_kernel<<<dim3(512 * 512 / 256, 3), 256, 0, stream>>>(Wk, Wq, Wv, Wt);
    proj_kernel<<<dim3(64, 4, 3), 256, 0, stream>>>(
        keys, queries, values, Wt, KQVb);
    attn_kernel<<<dim3(512), dim3(512), 0, stream>>>(
        Qb, Kb, Vb, key_seq, (float*)d_out);
}